// Round 2
// baseline (161.436 us; speedup 1.0000x reference)
//
#include <hip/hip_runtime.h>

// LSTM B=32768, T=50, I=2, H=32.
// R14: occupancy split. R13 measured VALUBusy 52% / Occ 17.8% with only
// 2 waves/SIMD (2048 waves = B/16) -> latency-bound, port half idle.
// Split the 32 hidden units across 2 cooperating waves per 16-row group:
//   wave w owns units 16w..16w+15 (all 4 gates, its c/h recurrence slice),
//   full h exchanged via double-buffered LDS planes, 1 barrier/t.
// 4096 waves -> 4 waves/SIMD. Per-wave-t work halves (20 exp + 4 rcp,
// 16 gate MFMAs + amortized head); total port work invariant; latency hidden.
// Key layout trick: k-axis permutation unit(q*8+2p)=q*4+p, unit(q*8+2p+1)=
// q*4+p+16 (applied consistently to all B-frags) => plane word j =
// [bf16 h_j | bf16 h_{j+16}]: each wave writes its half as ds_write_b16
// halfwords -- zero cross-lane packing. x pre-split-packed into 3 LDS
// planes at staging (no per-t Axf build). Head MFMAs alternate by t parity.
// Carried from R13: MFMA ci-init (x-proj+bias as 4th MFMA), row-pair pk
// activations, split-precision h (hh*Wh+hl*Wh+hh*Bl), scales folded
// (-log2e/+2log2e), clamps on zg and c only (CL=14), batched reciprocals.

#define TS 50
#define HSTR 20     // u32 stride of h plane rows (80 B): 16B-aligned b128
#define XSTR 52     // u32 stride of x plane rows
#define CL 14.0f

typedef short short8 __attribute__((ext_vector_type(8)));
typedef float f32x4 __attribute__((ext_vector_type(4)));
typedef float f32x2 __attribute__((ext_vector_type(2)));

__device__ __forceinline__ float fast_exp2(float x) {
    return __builtin_amdgcn_exp2f(x);
}
__device__ __forceinline__ float fast_rcp(float x) {
    return __builtin_amdgcn_rcpf(x);
}
__device__ __forceinline__ f32x2 pexp(f32x2 z) {           // scalar trans x2
    f32x2 r; r.x = fast_exp2(z.x); r.y = fast_exp2(z.y); return r;
}
__device__ __forceinline__ f32x2 prcp(f32x2 v) {           // scalar trans x2
    f32x2 r; r.x = fast_rcp(v.x); r.y = fast_rcp(v.y); return r;
}
__device__ __forceinline__ f32x2 vmin2(f32x2 v, float s) { // -> v_pk_min_f32
    f32x2 r; r.x = fminf(v.x, s); r.y = fminf(v.y, s); return r;
}
// v ~= hi + lo (bf16 each, trunc). returns (lo<<16)|hi
__device__ __forceinline__ unsigned split_pack(float v) {
    unsigned u   = __float_as_uint(v);
    float    res = v - __uint_as_float(u & 0xffff0000u);
    return __builtin_amdgcn_perm(__float_as_uint(res), u, 0x07060302u);
}
// (a & 0xffff) | (b << 16)
__device__ __forceinline__ unsigned lo_pair(unsigned a, unsigned b) {
    return __builtin_amdgcn_perm(b, a, 0x05040100u);
}
// (a >> 16) | (b & 0xffff0000)
__device__ __forceinline__ unsigned hi_pair(unsigned a, unsigned b) {
    return __builtin_amdgcn_perm(b, a, 0x07060302u);
}

union U4S8 { uint4 v; short8 s; unsigned u[4]; };

__global__ __launch_bounds__(128, 4)
void lsnn_kernel(const float* __restrict__ x,
                 const float* __restrict__ W_ih,
                 const float* __restrict__ W_hh,
                 const float* __restrict__ b_ih,
                 const float* __restrict__ b_hh,
                 const float* __restrict__ W_out,
                 const float* __restrict__ b_out,
                 const float* __restrict__ h0,
                 const float* __restrict__ c0,
                 float* __restrict__ out)
{
    // LDS: x planes 9984 B + h planes 5120 B + out 3200 B = 18304 B/block
    // -> 8 blocks/CU (160 KiB), 16 waves/CU, 4 waves/SIMD.
    __shared__ __align__(16) unsigned xa0[16 * XSTR];
    __shared__ __align__(16) unsigned xa1[16 * XSTR];
    __shared__ __align__(16) unsigned xa2[16 * XSTR];
    __shared__ __align__(16) unsigned hhi[2][16 * HSTR];  // [buf][row][j]
    __shared__ __align__(16) unsigned hlo[2][16 * HSTR];
    __shared__ __align__(16) float    ow[16 * TS];

    const int  tid  = threadIdx.x;
    const int  wv   = tid >> 6;        // cooperating wave 0/1: units 16wv..+15
    const int  lane = tid & 63;
    const int  u0   = lane & 15;
    const int  q    = lane >> 4;
    const long b0   = (long)blockIdx.x * 16;

    // ---- stage x split-packed into 3 planes: a0, a1, lo_pair(a0,a1) ----
    for (int i = tid; i < 800; i += 128) {
        int row = i / 50, t = i - row * 50;          // setup-only divide
        float2 v = *(const float2*)(x + (b0 + row) * 100 + 2 * t);
        unsigned a0 = split_pack(v.x), a1 = split_pack(v.y);
        xa0[row * XSTR + t] = a0;
        xa1[row * XSTR + t] = a1;
        xa2[row * XSTR + t] = lo_pair(a0, a1);
    }
    // ---- stage h0 into buf 0: word j = [bf16 h_j | bf16 h_{j+16}] ----
    for (int i = tid; i < 512; i += 128) {
        int row = i >> 5, u = i & 31;
        int j = u & 15, half = u >> 4;
        unsigned p = split_pack(h0[b0 * 32 + i]);    // (lo<<16)|hi
        ((unsigned short*)&hhi[0][row * HSTR + j])[half] = (unsigned short)(p & 0xffffu);
        ((unsigned short*)&hlo[0][row * HSTR + j])[half] = (unsigned short)(p >> 16);
    }

    const float L2E = 1.4426950408889634f;
    const float SG  = 2.0f * L2E;

    // ---- W_hh B-tiles (4): tile n = gate n, col u0 -> unit 16wv+u0 ----
    // k-permutation: word p of A/B frag = units (q*4+p, q*4+p+16)
    short8 Bh[4], Bl[4], Bx[4];
    #pragma unroll
    for (int n = 0; n < 4; ++n) {
        const float s  = (n == 2) ? SG : -L2E;
        const int   gg = n * 32 + 16 * wv + u0;
        const float* wr = W_hh + gg * 32;
        U4S8 uh, ul;
        #pragma unroll
        for (int p = 0; p < 4; ++p) {
            unsigned p0 = split_pack(wr[q * 4 + p]      * s);
            unsigned p1 = split_pack(wr[q * 4 + p + 16] * s);
            uh.u[p] = lo_pair(p0, p1);   // [hi(u_j), hi(u_{j+16})]
            ul.u[p] = hi_pair(p0, p1);   // [lo(u_j), lo(u_{j+16})]
        }
        Bh[n] = uh.s;  Bl[n] = ul.s;
        U4S8 ux;
        if (q == 0) {                    // ci rows k=0..7 live in q==0 lanes
            unsigned s0 = split_pack(W_ih[gg * 2 + 0] * s);
            unsigned s1 = split_pack(W_ih[gg * 2 + 1] * s);
            unsigned sb = split_pack((b_ih[gg] + b_hh[gg]) * s);
            ux.u[0] = lo_pair(s0, s0);   // [wh0, wh0]
            ux.u[1] = lo_pair(s1, s1);   // [wh1, wh1]
            ux.u[2] = hi_pair(s0, s1);   // [wl0, wl1]
            ux.u[3] = sb;                // [bh,  bl ]
        } else {
            ux.u[0] = 0u; ux.u[1] = 0u; ux.u[2] = 0u; ux.u[3] = 0u;
        }
        Bx[n] = ux.s;
    }
    // ---- head B-frag: B[k][n] = w_out[unit(k)] replicated over n ----
    short8 Bwh, Bwl;
    {
        U4S8 uh, ul;
        #pragma unroll
        for (int p = 0; p < 4; ++p) {
            unsigned p0 = split_pack(W_out[q * 4 + p]);
            unsigned p1 = split_pack(W_out[q * 4 + p + 16]);
            uh.u[p] = lo_pair(p0, p1);
            ul.u[p] = hi_pair(p0, p1);
        }
        Bwh = uh.s;  Bwl = ul.s;
    }
    const float bout = b_out[0];

    // ---- c-state: rows (q*4+2rr, q*4+2rr+1), unit 16wv+u0 ----
    f32x2 cst2[2];
    #pragma unroll
    for (int rr = 0; rr < 2; ++rr) {
        cst2[rr].x = c0[(b0 + q * 4 + 2 * rr    ) * 32 + 16 * wv + u0];
        cst2[rr].y = c0[(b0 + q * 4 + 2 * rr + 1) * 32 + 16 * wv + u0];
    }

    __syncthreads();

    const f32x4 ZV = {0.f, 0.f, 0.f, 0.f};
    const int abase = u0 * HSTR + q * 4;
    int cur = 0;

    #pragma unroll 1
    for (int t = 0; t < TS; ++t) {
        // ---- A-fragment h_t: row u0, words q*4..q*4+3 of buf cur ----
        U4S8 Ahh, Ahl;
        Ahh.v = *(const uint4*)&hhi[cur][abase];
        Ahl.v = *(const uint4*)&hlo[cur][abase];

        // ---- Ax frag from pre-packed planes (row u0, broadcast over q) ----
        U4S8 Axf;
        Axf.u[0] = xa0[u0 * XSTR + t];
        Axf.u[1] = xa1[u0 * XSTR + t];
        Axf.u[2] = xa2[u0 * XSTR + t];
        Axf.u[3] = 0x3f803f80u;          // [1.0, 1.0] bf16

        // ---- output head for h_t (alternate waves by t parity) ----
        if (t > 0 && (t & 1) == wv) {
            f32x4 aw = ZV;
            aw = __builtin_amdgcn_mfma_f32_16x16x32_bf16(Ahh.s, Bwh, aw, 0, 0, 0);
            aw = __builtin_amdgcn_mfma_f32_16x16x32_bf16(Ahl.s, Bwh, aw, 0, 0, 0);
            aw = __builtin_amdgcn_mfma_f32_16x16x32_bf16(Ahh.s, Bwl, aw, 0, 0, 0);
            if (u0 == 0) {
                #pragma unroll
                for (int r = 0; r < 4; ++r)
                    ow[(q * 4 + r) * TS + (t - 1)] = aw[r] + bout;
            }
        }

        // ---- gates: ci-MFMA + 3 split-h MFMAs per tile (4 tiles) ----
        f32x4 acc[4];
        #pragma unroll
        for (int n = 0; n < 4; ++n)
            acc[n] = __builtin_amdgcn_mfma_f32_16x16x32_bf16(Axf.s, Bx[n], ZV, 0, 0, 0);
        #pragma unroll
        for (int n = 0; n < 4; ++n) {
            acc[n] = __builtin_amdgcn_mfma_f32_16x16x32_bf16(Ahh.s, Bh[n], acc[n], 0, 0, 0);
            acc[n] = __builtin_amdgcn_mfma_f32_16x16x32_bf16(Ahl.s, Bh[n], acc[n], 0, 0, 0);
            acc[n] = __builtin_amdgcn_mfma_f32_16x16x32_bf16(Ahh.s, Bl[n], acc[n], 0, 0, 0);
        }

        // ---- activations: 2 row-pair groups (adjacent quad elements) ----
        f32x2 Bv2[2], Cv2[2], P12[2], Ep2[2], PP2[2];
        #pragma unroll
        for (int rr = 0; rr < 2; ++rr) {
            f32x2 zi = {acc[0][2*rr], acc[0][2*rr+1]};
            f32x2 zf = {acc[1][2*rr], acc[1][2*rr+1]};
            f32x2 zg = vmin2((f32x2){acc[2][2*rr], acc[2][2*rr+1]}, CL);
            f32x2 zo = {acc[3][2*rr], acc[3][2*rr+1]};
            f32x2 Av = pexp(zi);          // e^{-i}
            Bv2[rr]  = pexp(zg);          // e^{2g}
            f32x2 Ev = pexp(zf);          // e^{-f}
            Cv2[rr]  = pexp(zo);          // e^{-o}
            f32x2 Ap = 1.0f + Av, Bp = 1.0f + Bv2[rr];
            Ep2[rr] = 1.0f + Ev;
            P12[rr] = Ap * Bp;
            PP2[rr] = P12[rr] * Ep2[rr];
        }
        f32x2 R2[2];
        {
            f32x2 pr = PP2[0] * PP2[1];
            f32x2 ri = prcp(pr);
            R2[0] = PP2[1] * ri;
            R2[1] = PP2[0] * ri;
        }
        f32x2 Dv2[2], Q2[2];
        #pragma unroll
        for (int rr = 0; rr < 2; ++rr) {
            f32x2 fv = P12[rr] * R2[rr];                      // sigmoid(f)
            f32x2 ig = (Bv2[rr] - 1.0f) * (Ep2[rr] * R2[rr]); // sig(i)*tanh(g)
            f32x2 c  = fv * cst2[rr] + ig;
            cst2[rr] = c;
            f32x2 zc = vmin2(c * SG, CL);
            Dv2[rr] = pexp(zc);                               // e^{2c}
            Q2[rr]  = (1.0f + Cv2[rr]) * (1.0f + Dv2[rr]);
        }
        f32x2 RQ2[2];
        {
            f32x2 qr = Q2[0] * Q2[1];
            f32x2 ri = prcp(qr);
            RQ2[0] = Q2[1] * ri;
            RQ2[1] = Q2[0] * ri;
        }
        // ---- h store: halfword wv of word u0, rows q*4+2rr+e, buf cur^1 ----
        #pragma unroll
        for (int rr = 0; rr < 2; ++rr) {
            f32x2 h2 = (Dv2[rr] - 1.0f) * RQ2[rr];            // sig(o)*tanh(c)
            #pragma unroll
            for (int e = 0; e < 2; ++e) {
                float hv = e ? h2.y : h2.x;
                unsigned u   = __float_as_uint(hv);
                unsigned res = __float_as_uint(hv - __uint_as_float(u & 0xffff0000u));
                const int row = q * 4 + 2 * rr + e;
                ((unsigned short*)&hhi[cur ^ 1][row * HSTR + u0])[wv] = (unsigned short)(u >> 16);
                ((unsigned short*)&hlo[cur ^ 1][row * HSTR + u0])[wv] = (unsigned short)(res >> 16);
            }
        }
        __syncthreads();
        cur ^= 1;
    }

    // ---- final head for h_50 (wave 0; cur==0 after 50 flips) ----
    if (wv == 0) {
        U4S8 Ahh, Ahl;
        Ahh.v = *(const uint4*)&hhi[cur][abase];
        Ahl.v = *(const uint4*)&hlo[cur][abase];
        f32x4 aw = {0.f, 0.f, 0.f, 0.f};
        aw = __builtin_amdgcn_mfma_f32_16x16x32_bf16(Ahh.s, Bwh, aw, 0, 0, 0);
        aw = __builtin_amdgcn_mfma_f32_16x16x32_bf16(Ahl.s, Bwh, aw, 0, 0, 0);
        aw = __builtin_amdgcn_mfma_f32_16x16x32_bf16(Ahh.s, Bwl, aw, 0, 0, 0);
        if (u0 == 0) {
            #pragma unroll
            for (int r = 0; r < 4; ++r)
                ow[(q * 4 + r) * TS + 49] = aw[r] + bout;
        }
    }
    __syncthreads();

    // ---- coalesced flush of the block's 800 contiguous floats ----
    {
        float4* od = (float4*)(out + b0 * 50);
        const float4* os = (const float4*)ow;
        for (int i = tid; i < 200; i += 128) od[i] = os[i];
    }
}

extern "C" void kernel_launch(void* const* d_in, const int* in_sizes, int n_in,
                              void* d_out, int out_size, void* d_ws, size_t ws_size,
                              hipStream_t stream) {
    const float* x     = (const float*)d_in[0];
    const float* W_ih  = (const float*)d_in[1];
    const float* W_hh  = (const float*)d_in[2];
    const float* b_ih  = (const float*)d_in[3];
    const float* b_hh  = (const float*)d_in[4];
    const float* W_out = (const float*)d_in[5];
    const float* b_out = (const float*)d_in[6];
    const float* h0    = (const float*)d_in[7];
    const float* c0    = (const float*)d_in[8];
    float* out = (float*)d_out;

    dim3 grid(32768 / 16), block(128);
    lsnn_kernel<<<grid, block, 0, stream>>>(x, W_ih, W_hh, b_ih, b_hh,
                                            W_out, b_out, h0, c0, out);
}

// Round 3
// 153.444 us; speedup vs baseline: 1.0521x; 1.0521x over previous
//
#include <hip/hip_runtime.h>

// LSTM B=32768, T=50, I=2, H=32.
// R15: transposed-GEMM register-resident recurrence.
// R13/R14 showed wall invariant (~97-101us) across occupancy 2->4 waves/SIMD
// with identical total arithmetic => issue/throughput-bound at delivered
// clock, with the per-t LDS h round-trip (write->read->MFMA) in the chain.
// Fix: swap MFMA operands. A = W (stationary in VGPRs), B = h, so
// D[gate-unit][batch]: lane (q,u0) owns batch u0, units q*4+r (+16),
// which are EXACTLY the B-frag k-slots it supplies next t under the
// k-permutation ku(q*8+2p+e) = q*4+p+16e (verified by the passing R13/R14
// kernels on both operands). h never touches LDS: packed to bf16 hi/lo
// B-frag words in-register via v_cvt_pk_bf16_f32 (RNE; better than the old
// truncating split). Per wave-t removed: 2 ds_read_b128 + 8 ds_write_b16 +
// 8 perms + Axf build + 3/4 head stores + all h lgkmcnt waits + barrier.
// Inner loop LDS: 3 broadcast x-plane reads + 1 out write (q==0). Cost:
// stationary W frags -> ~170 VGPR -> 2 waves/SIMD (occupancy proven
// non-binding in R14).
// Carried: MFMA ci-init (x-proj+bias as 4th MFMA/tile), row-pair pk
// activations, split-precision h and W (3-term hh*Wh+hl*Wh+hh*Wl), scales
// folded (-log2e/+2log2e), clamps on zg and c only (CL=14), batched rcp.

#define TS 50
#define XSTR 51     // u32 stride of x plane rows (odd: conflict-free bcast)
#define CL 14.0f
#define WPB 4       // waves per block (independent; no barriers)

typedef short short8 __attribute__((ext_vector_type(8)));
typedef float f32x4 __attribute__((ext_vector_type(4)));
typedef float f32x2 __attribute__((ext_vector_type(2)));

__device__ __forceinline__ float fast_exp2(float x) {
    return __builtin_amdgcn_exp2f(x);
}
__device__ __forceinline__ float fast_rcp(float x) {
    return __builtin_amdgcn_rcpf(x);
}
__device__ __forceinline__ f32x2 pexp(f32x2 z) {           // scalar trans x2
    f32x2 r; r.x = fast_exp2(z.x); r.y = fast_exp2(z.y); return r;
}
__device__ __forceinline__ f32x2 prcp(f32x2 v) {           // scalar trans x2
    f32x2 r; r.x = fast_rcp(v.x); r.y = fast_rcp(v.y); return r;
}
__device__ __forceinline__ f32x2 vmin2(f32x2 v, float s) { // -> v_pk_min_f32
    f32x2 r; r.x = fminf(v.x, s); r.y = fminf(v.y, s); return r;
}
// v ~= hi + lo (bf16 each, trunc). returns (lo<<16)|hi
__device__ __forceinline__ unsigned split_pack(float v) {
    unsigned u   = __float_as_uint(v);
    float    res = v - __uint_as_float(u & 0xffff0000u);
    return __builtin_amdgcn_perm(__float_as_uint(res), u, 0x07060302u);
}
// (a & 0xffff) | (b << 16)
__device__ __forceinline__ unsigned lo_pair(unsigned a, unsigned b) {
    return __builtin_amdgcn_perm(b, a, 0x05040100u);
}
// (a >> 16) | (b & 0xffff0000)
__device__ __forceinline__ unsigned hi_pair(unsigned a, unsigned b) {
    return __builtin_amdgcn_perm(b, a, 0x07060302u);
}
// RNE split: whi = [bf16(a) | bf16(b)], wlo = [bf16(a-hi(a)) | bf16(b-hi(b))]
__device__ __forceinline__ void pack2(float a, float b,
                                      unsigned &whi, unsigned &wlo) {
    unsigned h, l;
    asm("v_cvt_pk_bf16_f32 %0, %1, %2" : "=v"(h) : "v"(a), "v"(b));
    float ra = a - __uint_as_float(h << 16);
    float rb = b - __uint_as_float(h & 0xffff0000u);
    asm("v_cvt_pk_bf16_f32 %0, %1, %2" : "=v"(l) : "v"(ra), "v"(rb));
    whi = h; wlo = l;
}

union U4S8 { uint4 v; short8 s; unsigned u[4]; };

__global__ __launch_bounds__(256, 2)
void lsnn_kernel(const float* __restrict__ x,
                 const float* __restrict__ W_ih,
                 const float* __restrict__ W_hh,
                 const float* __restrict__ b_ih,
                 const float* __restrict__ b_hh,
                 const float* __restrict__ W_out,
                 const float* __restrict__ b_out,
                 const float* __restrict__ h0,
                 const float* __restrict__ c0,
                 float* __restrict__ out)
{
    // LDS: 3 x-planes (3264 B/wave each) + out (3200 B/wave) = 52 KB/block.
    __shared__ __align__(16) unsigned xa0[WPB][16 * XSTR];
    __shared__ __align__(16) unsigned xa1[WPB][16 * XSTR];
    __shared__ __align__(16) unsigned xa2[WPB][16 * XSTR];
    __shared__ __align__(16) float    out_lds[WPB][16 * TS];

    const int  tid  = threadIdx.x;
    const int  g_w  = tid >> 6;
    const int  lane = tid & 63;
    const int  u0   = lane & 15;     // batch column (this lane's batch row)
    const int  q    = lane >> 4;     // k-block / D-row group
    const long b0   = ((long)blockIdx.x * WPB + g_w) * 16;

    unsigned* x0w = xa0[g_w];
    unsigned* x1w = xa1[g_w];
    unsigned* x2w = xa2[g_w];
    float*    ow  = out_lds[g_w];

    // ---- stage x split-packed into 3 planes (per-wave private) ----
    for (int i = lane; i < 800; i += 64) {
        int row = i / 50, t = i - row * 50;          // setup-only divide
        float2 v = *(const float2*)(x + (b0 + row) * 100 + 2 * t);
        unsigned a0 = split_pack(v.x), a1 = split_pack(v.y);
        x0w[row * XSTR + t] = a0;                    // [xh0 | xl0]
        x1w[row * XSTR + t] = a1;                    // [xh1 | xl1]
        x2w[row * XSTR + t] = lo_pair(a0, a1);       // [xh0 | xh1]
    }

    const float L2E = 1.4426950408889634f;
    const float SG  = 2.0f * L2E;

    // ---- stationary A-frags: tile n = ub*4 + gate; D-row m -> W_hh row
    //      R = gate*32 + ub*16 + m.  A word p = units (q*4+p, q*4+p+16). ----
    short8 Awh[8], Awl[8], Aci[8];
    #pragma unroll
    for (int n = 0; n < 8; ++n) {
        const int   g  = n & 3, ub = n >> 2;
        const float s  = (g == 2) ? SG : -L2E;
        const int   R  = g * 32 + ub * 16 + u0;
        const float* wr = W_hh + R * 32;
        U4S8 uh, ul;
        #pragma unroll
        for (int p = 0; p < 4; ++p) {
            unsigned p0 = split_pack(wr[q * 4 + p]      * s);
            unsigned p1 = split_pack(wr[q * 4 + p + 16] * s);
            uh.u[p] = lo_pair(p0, p1);
            ul.u[p] = hi_pair(p0, p1);
        }
        Awh[n] = uh.s;  Awl[n] = ul.s;
        U4S8 ux;
        if (q == 0) {   // ci k-rows 0..7: [wh0,wh0,wh1,wh1,wl0,wl1,bh,bl]
            unsigned s0 = split_pack(W_ih[R * 2 + 0] * s);
            unsigned s1 = split_pack(W_ih[R * 2 + 1] * s);
            unsigned sb = split_pack((b_ih[R] + b_hh[R]) * s);
            ux.u[0] = lo_pair(s0, s0);
            ux.u[1] = lo_pair(s1, s1);
            ux.u[2] = hi_pair(s0, s1);
            ux.u[3] = sb;
        } else {
            ux.u[0] = 0u; ux.u[1] = 0u; ux.u[2] = 0u; ux.u[3] = 0u;
        }
        Aci[n] = ux.s;
    }
    // ---- head A-frags: A[m][k] = W_out[ku(k)], uniform over m ----
    short8 Awoh, Awol;
    {
        U4S8 uh, ul;
        #pragma unroll
        for (int p = 0; p < 4; ++p) {
            unsigned p0 = split_pack(W_out[q * 4 + p]);
            unsigned p1 = split_pack(W_out[q * 4 + p + 16]);
            uh.u[p] = lo_pair(p0, p1);
            ul.u[p] = hi_pair(p0, p1);
        }
        Awoh = uh.s;  Awol = ul.s;
    }
    const float bout = b_out[0];

    // ---- h0 -> B-frags (register-resident recurrent state) ----
    U4S8 Bhh, Bhl;
    {
        const float* hp = h0 + (b0 + u0) * 32 + q * 4;
        float4 ha = *(const float4*)hp;
        float4 hb = *(const float4*)(hp + 16);
        pack2(ha.x, hb.x, Bhh.u[0], Bhl.u[0]);
        pack2(ha.y, hb.y, Bhh.u[1], Bhl.u[1]);
        pack2(ha.z, hb.z, Bhh.u[2], Bhl.u[2]);
        pack2(ha.w, hb.w, Bhh.u[3], Bhl.u[3]);
    }
    // ---- c0: group gi = ub*2+rr -> units ub*16+q*4+(2rr, 2rr+1) ----
    f32x2 cst2[4];
    #pragma unroll
    for (int ub = 0; ub < 2; ++ub)
        #pragma unroll
        for (int rr = 0; rr < 2; ++rr)
            cst2[ub * 2 + rr] =
                *(const f32x2*)(c0 + (b0 + u0) * 32 + ub * 16 + q * 4 + 2 * rr);

    const f32x4 ZV = {0.f, 0.f, 0.f, 0.f};
    const int xbase = u0 * XSTR;

    // ---- x prefetch for t=0 (broadcast across q) ----
    unsigned xw0 = x0w[xbase], xw1 = x1w[xbase], xw2 = x2w[xbase];

    #pragma unroll 1
    for (int t = 0; t < TS; ++t) {
        U4S8 Bx;
        Bx.u[0] = xw0;  Bx.u[1] = xw1;  Bx.u[2] = xw2;
        Bx.u[3] = 0x3f803f80u;          // [1.0, 1.0] bf16
        if (t + 1 < TS) {
            xw0 = x0w[xbase + t + 1];
            xw1 = x1w[xbase + t + 1];
            xw2 = x2w[xbase + t + 1];
        }

        // ---- output head for h_t (skip t=0): D rows all equal ----
        if (t > 0) {
            f32x4 aw = ZV;
            aw = __builtin_amdgcn_mfma_f32_16x16x32_bf16(Awoh, Bhh.s, aw, 0, 0, 0);
            aw = __builtin_amdgcn_mfma_f32_16x16x32_bf16(Awoh, Bhl.s, aw, 0, 0, 0);
            aw = __builtin_amdgcn_mfma_f32_16x16x32_bf16(Awol, Bhh.s, aw, 0, 0, 0);
            if (q == 0) ow[u0 * TS + (t - 1)] = aw[0] + bout;
        }

        // ---- gates: ci-MFMA + 3 split MFMAs per tile ----
        f32x4 acc[8];
        #pragma unroll
        for (int n = 0; n < 8; ++n)
            acc[n] = __builtin_amdgcn_mfma_f32_16x16x32_bf16(Aci[n], Bx.s, ZV, 0, 0, 0);
        #pragma unroll
        for (int n = 0; n < 8; ++n) {
            acc[n] = __builtin_amdgcn_mfma_f32_16x16x32_bf16(Awh[n], Bhh.s, acc[n], 0, 0, 0);
            acc[n] = __builtin_amdgcn_mfma_f32_16x16x32_bf16(Awh[n], Bhl.s, acc[n], 0, 0, 0);
            acc[n] = __builtin_amdgcn_mfma_f32_16x16x32_bf16(Awl[n], Bhh.s, acc[n], 0, 0, 0);
        }

        // ---- activations: 4 row-pair groups gi = ub*2+rr ----
        f32x2 Bv2[4], Cv2[4], P12[4], Ep2[4], PP2[4];
        #pragma unroll
        for (int ub = 0; ub < 2; ++ub) {
            #pragma unroll
            for (int rr = 0; rr < 2; ++rr) {
                const int gi = ub * 2 + rr, nb = ub * 4;
                f32x2 zi = {acc[nb + 0][2*rr], acc[nb + 0][2*rr + 1]};
                f32x2 zf = {acc[nb + 1][2*rr], acc[nb + 1][2*rr + 1]};
                f32x2 zg = vmin2((f32x2){acc[nb + 2][2*rr], acc[nb + 2][2*rr + 1]}, CL);
                f32x2 zo = {acc[nb + 3][2*rr], acc[nb + 3][2*rr + 1]};
                f32x2 Av = pexp(zi);          // e^{-i}
                Bv2[gi]  = pexp(zg);          // e^{2g}
                f32x2 Ev = pexp(zf);          // e^{-f}
                Cv2[gi]  = pexp(zo);          // e^{-o}
                f32x2 Ap = 1.0f + Av, Bp = 1.0f + Bv2[gi];
                Ep2[gi] = 1.0f + Ev;
                P12[gi] = Ap * Bp;
                PP2[gi] = P12[gi] * Ep2[gi];
            }
        }
        f32x2 R2[4];
        #pragma unroll
        for (int bb = 0; bb < 2; ++bb) {
            f32x2 pr = PP2[2*bb] * PP2[2*bb + 1];
            f32x2 ri = prcp(pr);
            R2[2*bb]     = PP2[2*bb + 1] * ri;
            R2[2*bb + 1] = PP2[2*bb]     * ri;
        }
        f32x2 Dv2[4], Q2[4];
        #pragma unroll
        for (int gi = 0; gi < 4; ++gi) {
            f32x2 fv = P12[gi] * R2[gi];                      // sigmoid(f)
            f32x2 ig = (Bv2[gi] - 1.0f) * (Ep2[gi] * R2[gi]); // sig(i)*tanh(g)
            f32x2 c  = fv * cst2[gi] + ig;
            cst2[gi] = c;
            f32x2 zc = vmin2(c * SG, CL);
            Dv2[gi] = pexp(zc);                               // e^{2c}
            Q2[gi]  = (1.0f + Cv2[gi]) * (1.0f + Dv2[gi]);
        }
        f32x2 RQ2[4];
        #pragma unroll
        for (int bb = 0; bb < 2; ++bb) {
            f32x2 qr = Q2[2*bb] * Q2[2*bb + 1];
            f32x2 ri = prcp(qr);
            RQ2[2*bb]     = Q2[2*bb + 1] * ri;
            RQ2[2*bb + 1] = Q2[2*bb]     * ri;
        }
        // ---- h in registers -> B-frag words [h(u), h(u+16)] ----
        float hub[2][4];
        #pragma unroll
        for (int gi = 0; gi < 4; ++gi) {
            f32x2 h2 = (Dv2[gi] - 1.0f) * RQ2[gi];            // sig(o)*tanh(c)
            hub[gi >> 1][2 * (gi & 1)]     = h2.x;
            hub[gi >> 1][2 * (gi & 1) + 1] = h2.y;
        }
        #pragma unroll
        for (int p = 0; p < 4; ++p)
            pack2(hub[0][p], hub[1][p], Bhh.u[p], Bhl.u[p]);
    }

    // ---- final head for h_50 ----
    {
        f32x4 aw = {0.f, 0.f, 0.f, 0.f};
        aw = __builtin_amdgcn_mfma_f32_16x16x32_bf16(Awoh, Bhh.s, aw, 0, 0, 0);
        aw = __builtin_amdgcn_mfma_f32_16x16x32_bf16(Awoh, Bhl.s, aw, 0, 0, 0);
        aw = __builtin_amdgcn_mfma_f32_16x16x32_bf16(Awol, Bhh.s, aw, 0, 0, 0);
        if (q == 0) ow[u0 * TS + 49] = aw[0] + bout;
    }

    // ---- coalesced flush of this wave's 800 contiguous floats ----
    {
        float4* od = (float4*)(out + b0 * 50);
        const float4* os = (const float4*)ow;
        for (int i = lane; i < 200; i += 64) od[i] = os[i];
    }
}

extern "C" void kernel_launch(void* const* d_in, const int* in_sizes, int n_in,
                              void* d_out, int out_size, void* d_ws, size_t ws_size,
                              hipStream_t stream) {
    const float* x     = (const float*)d_in[0];
    const float* W_ih  = (const float*)d_in[1];
    const float* W_hh  = (const float*)d_in[2];
    const float* b_ih  = (const float*)d_in[3];
    const float* b_hh  = (const float*)d_in[4];
    const float* W_out = (const float*)d_in[5];
    const float* b_out = (const float*)d_in[6];
    const float* h0    = (const float*)d_in[7];
    const float* c0    = (const float*)d_in[8];
    float* out = (float*)d_out;

    dim3 grid(32768 / (16 * WPB)), block(64 * WPB);
    lsnn_kernel<<<grid, block, 0, stream>>>(x, W_ih, W_hh, b_ih, b_hh,
                                            W_out, b_out, h0, c0, out);
}